// Round 2
// baseline (197.672 us; speedup 1.0000x reference)
//
#include <hip/hip_runtime.h>
#include <hip/hip_bf16.h>

#define N_NODES 100000
#define N_EDGES 800000
#define HIDDEN 128
#define N_TILES 1563            // ceil(100000 / 64)
#define PC_GRID 1024            // R12: 4 blocks/CU residency (LDS 32 KB, VGPR<=128)

typedef short frag_ab __attribute__((ext_vector_type(8)));   // 8 x bf16
typedef float frag_cd __attribute__((ext_vector_type(4)));   // 4 x f32

// round-to-nearest-even fp32 -> bf16 (scalar)
__device__ inline unsigned short f2b(float f) {
    union { float f; unsigned u; } x; x.f = f;
    return (unsigned short)((x.u + 0x7fffu + ((x.u >> 16) & 1u)) >> 16);
}

// packed pair fp32 -> bf16x2 (v_cvt_pk_bf16_f32 on gfx950)
__device__ inline unsigned pk2(float x, float y) {
    union { __hip_bfloat162 h; unsigned u; } c;
    c.h = __float22bfloat162_rn(make_float2(x, y));
    return c.u;
}

// ---------------------------------------------------------------------------
// Kernel 0: transpose+convert W1 (256x128 fp32) -> Bt[256][128] bf16, k-contig.
// ---------------------------------------------------------------------------
__global__ __launch_bounds__(256) void transpose_w1(
    const float* __restrict__ W1, unsigned short* __restrict__ Bt)
{
    const int t  = threadIdx.x;
    const int nc = blockIdx.x * 4 + (t >> 6);
    const int k2 = (t & 63) * 2;
    const int col  = nc & 127;
    const int roff = (nc >= 128) ? 128 : 0;
    float f0 = W1[(size_t)(roff + k2)     * HIDDEN + col];
    float f1 = W1[(size_t)(roff + k2 + 1) * HIDDEN + col];
    *(unsigned*)(Bt + (size_t)nc * HIDDEN + k2) = (unsigned)f2b(f0) | ((unsigned)f2b(f1) << 16);
}

// ---------------------------------------------------------------------------
// Kernel 1 (MFMA GEMM, persistent): UV = z @ [W1src|W1dst] + [b1|0] -> uint8.
// R12 change: C phase split into two 32-row half-tiles so the fp32 C staging
// needs 32 KB instead of 64 KB -> LDS/block 32 KB -> 4 blocks/CU (16 waves,
// was 8). R11's counters showed pure latency-bound (MfmaUtil 4.5, VALU 18,
// HBM 12.6%, occ 17.5%) with LDS the sole occupancy limiter (VGPR=116).
// Core A-staging / prefetch / K-loop / quant math unchanged (measured-best).
// ---------------------------------------------------------------------------
#define AS_STRIDE 136

__global__ __launch_bounds__(256, 4) void precompute_uv_mfma(
    const float* __restrict__ z, const unsigned short* __restrict__ Bt,
    const float* __restrict__ b1, unsigned char* __restrict__ UVq,
    float* __restrict__ scales)
{
    __shared__ float smemf[32 * 256];                 // 32 KB: A phase (u16 alias, 17.4 KB) / C half-tile (fp32)
    unsigned short* smem = (unsigned short*)smemf;
    const int t = threadIdx.x;
    const int lane = t & 63;
    const int w = t >> 6;
    const int wn = w * 64;
    const int g  = lane >> 4;
    const int lc = lane & 15;

    // --- B fragments + bias: once per block ---
    frag_ab b[4][4];
    float bias[4];
    #pragma unroll
    for (int nt = 0; nt < 4; ++nt) {
        int nc = wn + nt * 16 + lc;
        bias[nt] = (nc < HIDDEN) ? b1[nc] : 0.f;
        const unsigned short* brow = Bt + (size_t)nc * HIDDEN;
        #pragma unroll
        for (int q = 0; q < 4; ++q)
            b[nt][q] = *(const frag_ab*)(brow + q * 32 + g * 8);
    }

    int tile = blockIdx.x;
    uint2 pf[8];   // next A tile, already packed bf16 (16 VGPRs)
    #pragma unroll
    for (int i = 0; i < 8; ++i) {
        int f4 = i * 256 + t;
        int m = tile * 64 + (f4 >> 5);
        if (m >= N_NODES) m = N_NODES - 1;
        float4 v = ((const float4*)z)[(size_t)m * 32 + (f4 & 31)];
        pf[i].x = pk2(v.x, v.y);
        pf[i].y = pk2(v.z, v.w);
    }

    while (true) {
        // --- stage A: packed regs -> LDS ---
        #pragma unroll
        for (int i = 0; i < 8; ++i) {
            int f4 = i * 256 + t;
            *(uint2*)&smem[(f4 >> 5) * AS_STRIDE + (f4 & 31) * 4] = pf[i];
        }
        __syncthreads();

        // --- prefetch NEXT tile (hides HBM latency behind MFMA+epilogue) ---
        const int next = tile + PC_GRID;
        const bool have_next = (next < N_TILES);
        if (have_next) {
            #pragma unroll
            for (int i = 0; i < 8; ++i) {
                int f4 = i * 256 + t;
                int m = next * 64 + (f4 >> 5);
                if (m >= N_NODES) m = N_NODES - 1;
                float4 v = ((const float4*)z)[(size_t)m * 32 + (f4 & 31)];
                pf[i].x = pk2(v.x, v.y);
                pf[i].y = pk2(v.z, v.w);
            }
        }

        // --- K loop: 16 ds_read_b128 + 64 MFMA per wave ---
        frag_cd acc[4][4];
        #pragma unroll
        for (int mt = 0; mt < 4; ++mt)
            #pragma unroll
            for (int nt = 0; nt < 4; ++nt)
                acc[mt][nt] = (frag_cd){0.f, 0.f, 0.f, 0.f};
        #pragma unroll
        for (int q = 0; q < 4; ++q) {
            frag_ab a[4];
            #pragma unroll
            for (int mt = 0; mt < 4; ++mt)
                a[mt] = *(const frag_ab*)&smem[(mt * 16 + lc) * AS_STRIDE + q * 32 + g * 8];
            #pragma unroll
            for (int mt = 0; mt < 4; ++mt)
                #pragma unroll
                for (int nt = 0; nt < 4; ++nt)
                    acc[mt][nt] = __builtin_amdgcn_mfma_f32_16x16x32_bf16(
                        a[mt], b[nt][q], acc[mt][nt], 0, 0, 0);
        }
        __syncthreads();   // A phase over; smem becomes fp32 C (half-tiles)

        const int m0 = tile * 64;

        // --- two 32-row half-tiles: epilogue -> LDS fp32 (swizzled), quantize ---
        #pragma unroll
        for (int half = 0; half < 2; ++half) {
            // epilogue: acc[2h..2h+1][*] -> smemf rows 0..31 (local), col ^ (g<<4)
            #pragma unroll
            for (int nt = 0; nt < 4; ++nt) {
                int nc = wn + nt * 16 + lc;
                #pragma unroll
                for (int mh = 0; mh < 2; ++mh) {
                    int mt = half * 2 + mh;
                    #pragma unroll
                    for (int r = 0; r < 4; ++r) {
                        int row = mh * 16 + g * 4 + r;      // local 0..31
                        smemf[row * 256 + (nc ^ (g << 4))] = acc[mt][nt][r] + bias[nt];
                    }
                }
            }
            __syncthreads();

            // quantize + store: one row (256 f32) per wave per iter, 8 iters.
            // lane reads cols 4l..4l+3 (swizzle-corrected), half-wave abs-max,
            // q = trunc(x*127/max + 128.5), 256 B/row coalesced store.
            #pragma unroll
            for (int it = 0; it < 8; ++it) {
                const int row  = it * 4 + w;                 // local 0..31
                const int node = m0 + half * 32 + row;
                const int c    = (it & 3) << 4;              // == ((row>>2)&3)<<4
                float4 x = *(const float4*)&smemf[row * 256 + ((lane * 4) ^ c)];
                float mx = fmaxf(fmaxf(fabsf(x.x), fabsf(x.y)),
                                 fmaxf(fabsf(x.z), fabsf(x.w)));
                #pragma unroll
                for (int k = 1; k < 32; k <<= 1)
                    mx = fmaxf(mx, __shfl_xor(mx, k, 32));   // per-half reduce
                mx = fmaxf(mx, 1e-12f);
                const float ainv = 127.0f / mx;
                unsigned q0 = (unsigned)__builtin_fmaf(x.x, ainv, 128.5f);
                unsigned q1 = (unsigned)__builtin_fmaf(x.y, ainv, 128.5f);
                unsigned q2 = (unsigned)__builtin_fmaf(x.z, ainv, 128.5f);
                unsigned q3 = (unsigned)__builtin_fmaf(x.w, ainv, 128.5f);
                unsigned pack = q0 | (q1 << 8) | (q2 << 16) | (q3 << 24);
                if (node < N_NODES) {
                    *(unsigned*)&UVq[(size_t)node * 256 + lane * 4] = pack;
                    if ((lane & 31) == 0)
                        scales[node * 2 + (lane >> 5)] = mx * (1.0f / 127.0f);
                }
            }
            __syncthreads();   // quant reads done before next half / next stage
        }

        if (!have_next) break;
        tile = next;
    }
}

// ---------------------------------------------------------------------------
// Kernel 2: per-edge score = relu(aU*(u-128) + aV*(v-128)) . W2 + b2
// UNCHANGED from R11 (no longer the top kernel).
// ---------------------------------------------------------------------------
__device__ inline float dq4(unsigned uq, unsigned vq, float aU, float aV,
                            float k, float4 w, float acc) {
    #pragma unroll
    for (int b = 0; b < 4; ++b) {
        float uf = (float)((uq >> (8 * b)) & 0xffu);
        float vf = (float)((vq >> (8 * b)) & 0xffu);
        float h  = __builtin_fmaf(aU, uf, __builtin_fmaf(aV, vf, k));
        h = fmaxf(h, 0.f);
        float wv = (b == 0) ? w.x : (b == 1) ? w.y : (b == 2) ? w.z : w.w;
        acc = __builtin_fmaf(h, wv, acc);
    }
    return acc;
}

__global__ __launch_bounds__(256) void edge_score(
    const int* __restrict__ ei, const unsigned char* __restrict__ UVq,
    const float* __restrict__ scales, const float* __restrict__ W2,
    const float* __restrict__ B2, float* __restrict__ out)
{
    const int t = threadIdx.x;
    const int g = t & 7;
    const int slot = t >> 3;
    const int e0 = blockIdx.x * 64 + slot;
    const int e1 = e0 + 32;

    const float4* W24 = (const float4*)W2;
    const float4 w0 = W24[g * 4 + 0];
    const float4 w1 = W24[g * 4 + 1];
    const float4 w2 = W24[g * 4 + 2];
    const float4 w3 = W24[g * 4 + 3];

    const int s0 = ei[e0];
    const int d0 = ei[N_EDGES + e0];
    const int s1 = ei[e1];
    const int d1 = ei[N_EDGES + e1];

    // 16 B/lane x 8 lanes = one 128 B row-half per edge side (1 dwordx4 each)
    const uint4 u0 = *(const uint4*)(UVq + (size_t)s0 * 256 + g * 16);
    const uint4 v0 = *(const uint4*)(UVq + (size_t)d0 * 256 + 128 + g * 16);
    const uint4 u1 = *(const uint4*)(UVq + (size_t)s1 * 256 + g * 16);
    const uint4 v1 = *(const uint4*)(UVq + (size_t)d1 * 256 + 128 + g * 16);
    const float aU0 = scales[s0 * 2];
    const float aV0 = scales[d0 * 2 + 1];
    const float aU1 = scales[s1 * 2];
    const float aV1 = scales[d1 * 2 + 1];

    const float k0 = -128.f * (aU0 + aV0);
    const float k1 = -128.f * (aU1 + aV1);

    float A = 0.f, B = 0.f;
    A = dq4(u0.x, v0.x, aU0, aV0, k0, w0, A);
    A = dq4(u0.y, v0.y, aU0, aV0, k0, w1, A);
    A = dq4(u0.z, v0.z, aU0, aV0, k0, w2, A);
    A = dq4(u0.w, v0.w, aU0, aV0, k0, w3, A);

    B = dq4(u1.x, v1.x, aU1, aV1, k1, w0, B);
    B = dq4(u1.y, v1.y, aU1, aV1, k1, w1, B);
    B = dq4(u1.z, v1.z, aU1, aV1, k1, w2, B);
    B = dq4(u1.w, v1.w, aU1, aV1, k1, w3, B);

    float sa = A;
    float sb = B;
    sa += __shfl_xor(sa, 1, 8);
    sa += __shfl_xor(sa, 2, 8);
    sa += __shfl_xor(sa, 4, 8);
    sb += __shfl_xor(sb, 1, 8);
    sb += __shfl_xor(sb, 2, 8);
    sb += __shfl_xor(sb, 4, 8);

    if (g == 0) {
        float bb = B2[0];
        out[e0] = sa + bb;
        out[e1] = sb + bb;
    }
}

extern "C" void kernel_launch(void* const* d_in, const int* in_sizes, int n_in,
                              void* d_out, int out_size, void* d_ws, size_t ws_size,
                              hipStream_t stream) {
    const float* z  = (const float*)d_in[0];
    const int*   ei = (const int*)d_in[1];
    const float* W1 = (const float*)d_in[2];
    const float* b1 = (const float*)d_in[3];
    const float* W2 = (const float*)d_in[4];
    const float* b2 = (const float*)d_in[5];
    float* out = (float*)d_out;

    unsigned char* UVq = (unsigned char*)d_ws;                       // 25.6 MB
    float* scales = (float*)(UVq + (size_t)N_NODES * 256);           // 800 KB (U,V scale pairs)
    unsigned short* Bt = (unsigned short*)(scales + 2 * N_NODES);    // 64 KB, 16B-aligned

    transpose_w1<<<64, 256, 0, stream>>>(W1, Bt);
    precompute_uv_mfma<<<PC_GRID, 256, 0, stream>>>(z, Bt, b1, UVq, scales);
    edge_score<<<N_EDGES / 64, 256, 0, stream>>>(ei, UVq, scales, W2, b2, out);
}

// Round 3
// 151.335 us; speedup vs baseline: 1.3062x; 1.3062x over previous
//
#include <hip/hip_runtime.h>
#include <hip/hip_bf16.h>

#define N_NODES 100000
#define N_EDGES 800000
#define HIDDEN 128
#define N_TILES 1563            // ceil(100000 / 64)
#define PC_GRID 1024            // 4 blocks/CU residency (LDS 32 KB, natural VGPR ~116 <= 128)

typedef short frag_ab __attribute__((ext_vector_type(8)));   // 8 x bf16
typedef float frag_cd __attribute__((ext_vector_type(4)));   // 4 x f32

// round-to-nearest-even fp32 -> bf16 (scalar)
__device__ inline unsigned short f2b(float f) {
    union { float f; unsigned u; } x; x.f = f;
    return (unsigned short)((x.u + 0x7fffu + ((x.u >> 16) & 1u)) >> 16);
}

// packed pair fp32 -> bf16x2 (v_cvt_pk_bf16_f32 on gfx950)
__device__ inline unsigned pk2(float x, float y) {
    union { __hip_bfloat162 h; unsigned u; } c;
    c.h = __float22bfloat162_rn(make_float2(x, y));
    return c.u;
}

// ---------------------------------------------------------------------------
// Kernel 0: transpose+convert W1 (256x128 fp32) -> Bt[256][128] bf16, k-contig.
// ---------------------------------------------------------------------------
__global__ __launch_bounds__(256) void transpose_w1(
    const float* __restrict__ W1, unsigned short* __restrict__ Bt)
{
    const int t  = threadIdx.x;
    const int nc = blockIdx.x * 4 + (t >> 6);
    const int k2 = (t & 63) * 2;
    const int col  = nc & 127;
    const int roff = (nc >= 128) ? 128 : 0;
    float f0 = W1[(size_t)(roff + k2)     * HIDDEN + col];
    float f1 = W1[(size_t)(roff + k2 + 1) * HIDDEN + col];
    *(unsigned*)(Bt + (size_t)nc * HIDDEN + k2) = (unsigned)f2b(f0) | ((unsigned)f2b(f1) << 16);
}

// ---------------------------------------------------------------------------
// Kernel 1 (MFMA GEMM, persistent): UV = z @ [W1src|W1dst] + [b1|0] -> uint8.
// R13: R12's 32 KB half-tile C staging KEPT, but the __launch_bounds__(256,4)
// forcing REMOVED — it clamped VGPR 116->64 and spilled ~195 MB/dispatch
// (FETCH 25->104 MB, WRITE 26->143 MB, dur 52->89 us; same failure as R6).
// Natural allocation (R11: 116 VGPR) is spill-free and <=128, so HW residency
// is 4 blocks/CU from VGPR with LDS at 32 KB no longer the limiter.
// ---------------------------------------------------------------------------
#define AS_STRIDE 136

__global__ __launch_bounds__(256) void precompute_uv_mfma(
    const float* __restrict__ z, const unsigned short* __restrict__ Bt,
    const float* __restrict__ b1, unsigned char* __restrict__ UVq,
    float* __restrict__ scales)
{
    __shared__ float smemf[32 * 256];                 // 32 KB: A phase (u16 alias, 17.4 KB) / C half-tile (fp32)
    unsigned short* smem = (unsigned short*)smemf;
    const int t = threadIdx.x;
    const int lane = t & 63;
    const int w = t >> 6;
    const int wn = w * 64;
    const int g  = lane >> 4;
    const int lc = lane & 15;

    // --- B fragments + bias: once per block ---
    frag_ab b[4][4];
    float bias[4];
    #pragma unroll
    for (int nt = 0; nt < 4; ++nt) {
        int nc = wn + nt * 16 + lc;
        bias[nt] = (nc < HIDDEN) ? b1[nc] : 0.f;
        const unsigned short* brow = Bt + (size_t)nc * HIDDEN;
        #pragma unroll
        for (int q = 0; q < 4; ++q)
            b[nt][q] = *(const frag_ab*)(brow + q * 32 + g * 8);
    }

    int tile = blockIdx.x;
    uint2 pf[8];   // next A tile, already packed bf16 (16 VGPRs)
    #pragma unroll
    for (int i = 0; i < 8; ++i) {
        int f4 = i * 256 + t;
        int m = tile * 64 + (f4 >> 5);
        if (m >= N_NODES) m = N_NODES - 1;
        float4 v = ((const float4*)z)[(size_t)m * 32 + (f4 & 31)];
        pf[i].x = pk2(v.x, v.y);
        pf[i].y = pk2(v.z, v.w);
    }

    while (true) {
        // --- stage A: packed regs -> LDS ---
        #pragma unroll
        for (int i = 0; i < 8; ++i) {
            int f4 = i * 256 + t;
            *(uint2*)&smem[(f4 >> 5) * AS_STRIDE + (f4 & 31) * 4] = pf[i];
        }
        __syncthreads();

        // --- prefetch NEXT tile (hides HBM latency behind MFMA+epilogue) ---
        const int next = tile + PC_GRID;
        const bool have_next = (next < N_TILES);
        if (have_next) {
            #pragma unroll
            for (int i = 0; i < 8; ++i) {
                int f4 = i * 256 + t;
                int m = next * 64 + (f4 >> 5);
                if (m >= N_NODES) m = N_NODES - 1;
                float4 v = ((const float4*)z)[(size_t)m * 32 + (f4 & 31)];
                pf[i].x = pk2(v.x, v.y);
                pf[i].y = pk2(v.z, v.w);
            }
        }

        // --- K loop: 16 ds_read_b128 + 64 MFMA per wave ---
        frag_cd acc[4][4];
        #pragma unroll
        for (int mt = 0; mt < 4; ++mt)
            #pragma unroll
            for (int nt = 0; nt < 4; ++nt)
                acc[mt][nt] = (frag_cd){0.f, 0.f, 0.f, 0.f};
        #pragma unroll
        for (int q = 0; q < 4; ++q) {
            frag_ab a[4];
            #pragma unroll
            for (int mt = 0; mt < 4; ++mt)
                a[mt] = *(const frag_ab*)&smem[(mt * 16 + lc) * AS_STRIDE + q * 32 + g * 8];
            #pragma unroll
            for (int mt = 0; mt < 4; ++mt)
                #pragma unroll
                for (int nt = 0; nt < 4; ++nt)
                    acc[mt][nt] = __builtin_amdgcn_mfma_f32_16x16x32_bf16(
                        a[mt], b[nt][q], acc[mt][nt], 0, 0, 0);
        }
        __syncthreads();   // A phase over; smem becomes fp32 C (half-tiles)

        const int m0 = tile * 64;

        // --- two 32-row half-tiles: epilogue -> LDS fp32 (swizzled), quantize ---
        #pragma unroll
        for (int half = 0; half < 2; ++half) {
            // epilogue: acc[2h..2h+1][*] -> smemf rows 0..31 (local), col ^ (g<<4)
            #pragma unroll
            for (int nt = 0; nt < 4; ++nt) {
                int nc = wn + nt * 16 + lc;
                #pragma unroll
                for (int mh = 0; mh < 2; ++mh) {
                    int mt = half * 2 + mh;
                    #pragma unroll
                    for (int r = 0; r < 4; ++r) {
                        int row = mh * 16 + g * 4 + r;      // local 0..31
                        smemf[row * 256 + (nc ^ (g << 4))] = acc[mt][nt][r] + bias[nt];
                    }
                }
            }
            __syncthreads();

            // quantize + store: one row (256 f32) per wave per iter, 8 iters.
            // lane reads cols 4l..4l+3 (swizzle-corrected), half-wave abs-max,
            // q = trunc(x*127/max + 128.5), 256 B/row coalesced store.
            #pragma unroll
            for (int it = 0; it < 8; ++it) {
                const int row  = it * 4 + w;                 // local 0..31
                const int node = m0 + half * 32 + row;
                const int c    = (it & 3) << 4;              // == ((row>>2)&3)<<4
                float4 x = *(const float4*)&smemf[row * 256 + ((lane * 4) ^ c)];
                float mx = fmaxf(fmaxf(fabsf(x.x), fabsf(x.y)),
                                 fmaxf(fabsf(x.z), fabsf(x.w)));
                #pragma unroll
                for (int k = 1; k < 32; k <<= 1)
                    mx = fmaxf(mx, __shfl_xor(mx, k, 32));   // per-half reduce
                mx = fmaxf(mx, 1e-12f);
                const float ainv = 127.0f / mx;
                unsigned q0 = (unsigned)__builtin_fmaf(x.x, ainv, 128.5f);
                unsigned q1 = (unsigned)__builtin_fmaf(x.y, ainv, 128.5f);
                unsigned q2 = (unsigned)__builtin_fmaf(x.z, ainv, 128.5f);
                unsigned q3 = (unsigned)__builtin_fmaf(x.w, ainv, 128.5f);
                unsigned pack = q0 | (q1 << 8) | (q2 << 16) | (q3 << 24);
                if (node < N_NODES) {
                    *(unsigned*)&UVq[(size_t)node * 256 + lane * 4] = pack;
                    if ((lane & 31) == 0)
                        scales[node * 2 + (lane >> 5)] = mx * (1.0f / 127.0f);
                }
            }
            __syncthreads();   // quant reads done before next half / next stage
        }

        if (!have_next) break;
        tile = next;
    }
}

// ---------------------------------------------------------------------------
// Kernel 2: per-edge score = relu(aU*(u-128) + aV*(v-128)) . W2 + b2
// UNCHANGED from R11 (no longer the top kernel).
// ---------------------------------------------------------------------------
__device__ inline float dq4(unsigned uq, unsigned vq, float aU, float aV,
                            float k, float4 w, float acc) {
    #pragma unroll
    for (int b = 0; b < 4; ++b) {
        float uf = (float)((uq >> (8 * b)) & 0xffu);
        float vf = (float)((vq >> (8 * b)) & 0xffu);
        float h  = __builtin_fmaf(aU, uf, __builtin_fmaf(aV, vf, k));
        h = fmaxf(h, 0.f);
        float wv = (b == 0) ? w.x : (b == 1) ? w.y : (b == 2) ? w.z : w.w;
        acc = __builtin_fmaf(h, wv, acc);
    }
    return acc;
}

__global__ __launch_bounds__(256) void edge_score(
    const int* __restrict__ ei, const unsigned char* __restrict__ UVq,
    const float* __restrict__ scales, const float* __restrict__ W2,
    const float* __restrict__ B2, float* __restrict__ out)
{
    const int t = threadIdx.x;
    const int g = t & 7;
    const int slot = t >> 3;
    const int e0 = blockIdx.x * 64 + slot;
    const int e1 = e0 + 32;

    const float4* W24 = (const float4*)W2;
    const float4 w0 = W24[g * 4 + 0];
    const float4 w1 = W24[g * 4 + 1];
    const float4 w2 = W24[g * 4 + 2];
    const float4 w3 = W24[g * 4 + 3];

    const int s0 = ei[e0];
    const int d0 = ei[N_EDGES + e0];
    const int s1 = ei[e1];
    const int d1 = ei[N_EDGES + e1];

    // 16 B/lane x 8 lanes = one 128 B row-half per edge side (1 dwordx4 each)
    const uint4 u0 = *(const uint4*)(UVq + (size_t)s0 * 256 + g * 16);
    const uint4 v0 = *(const uint4*)(UVq + (size_t)d0 * 256 + 128 + g * 16);
    const uint4 u1 = *(const uint4*)(UVq + (size_t)s1 * 256 + g * 16);
    const uint4 v1 = *(const uint4*)(UVq + (size_t)d1 * 256 + 128 + g * 16);
    const float aU0 = scales[s0 * 2];
    const float aV0 = scales[d0 * 2 + 1];
    const float aU1 = scales[s1 * 2];
    const float aV1 = scales[d1 * 2 + 1];

    const float k0 = -128.f * (aU0 + aV0);
    const float k1 = -128.f * (aU1 + aV1);

    float A = 0.f, B = 0.f;
    A = dq4(u0.x, v0.x, aU0, aV0, k0, w0, A);
    A = dq4(u0.y, v0.y, aU0, aV0, k0, w1, A);
    A = dq4(u0.z, v0.z, aU0, aV0, k0, w2, A);
    A = dq4(u0.w, v0.w, aU0, aV0, k0, w3, A);

    B = dq4(u1.x, v1.x, aU1, aV1, k1, w0, B);
    B = dq4(u1.y, v1.y, aU1, aV1, k1, w1, B);
    B = dq4(u1.z, v1.z, aU1, aV1, k1, w2, B);
    B = dq4(u1.w, v1.w, aU1, aV1, k1, w3, B);

    float sa = A;
    float sb = B;
    sa += __shfl_xor(sa, 1, 8);
    sa += __shfl_xor(sa, 2, 8);
    sa += __shfl_xor(sa, 4, 8);
    sb += __shfl_xor(sb, 1, 8);
    sb += __shfl_xor(sb, 2, 8);
    sb += __shfl_xor(sb, 4, 8);

    if (g == 0) {
        float bb = B2[0];
        out[e0] = sa + bb;
        out[e1] = sb + bb;
    }
}

extern "C" void kernel_launch(void* const* d_in, const int* in_sizes, int n_in,
                              void* d_out, int out_size, void* d_ws, size_t ws_size,
                              hipStream_t stream) {
    const float* z  = (const float*)d_in[0];
    const int*   ei = (const int*)d_in[1];
    const float* W1 = (const float*)d_in[2];
    const float* b1 = (const float*)d_in[3];
    const float* W2 = (const float*)d_in[4];
    const float* b2 = (const float*)d_in[5];
    float* out = (float*)d_out;

    unsigned char* UVq = (unsigned char*)d_ws;                       // 25.6 MB
    float* scales = (float*)(UVq + (size_t)N_NODES * 256);           // 800 KB (U,V scale pairs)
    unsigned short* Bt = (unsigned short*)(scales + 2 * N_NODES);    // 64 KB, 16B-aligned

    transpose_w1<<<64, 256, 0, stream>>>(W1, Bt);
    precompute_uv_mfma<<<PC_GRID, 256, 0, stream>>>(z, Bt, b1, UVq, scales);
    edge_score<<<N_EDGES / 64, 256, 0, stream>>>(ei, UVq, scales, W2, b2, out);
}

// Round 4
// 142.684 us; speedup vs baseline: 1.3854x; 1.0606x over previous
//
#include <hip/hip_runtime.h>
#include <hip/hip_bf16.h>

#define N_NODES 100000
#define N_EDGES 800000
#define HIDDEN 128
#define N_TILES 1563            // ceil(100000 / 64)
#define PC_GRID 512             // R14: 2 blocks/CU x 256 CU (512-thread blocks, 16 waves/CU)

typedef short frag_ab __attribute__((ext_vector_type(8)));   // 8 x bf16
typedef float frag_cd __attribute__((ext_vector_type(4)));   // 4 x f32

// round-to-nearest-even fp32 -> bf16 (scalar)
__device__ inline unsigned short f2b(float f) {
    union { float f; unsigned u; } x; x.f = f;
    return (unsigned short)((x.u + 0x7fffu + ((x.u >> 16) & 1u)) >> 16);
}

// packed pair fp32 -> bf16x2 (v_cvt_pk_bf16_f32 on gfx950)
__device__ inline unsigned pk2(float x, float y) {
    union { __hip_bfloat162 h; unsigned u; } c;
    c.h = __float22bfloat162_rn(make_float2(x, y));
    return c.u;
}

// ---------------------------------------------------------------------------
// Kernel 0: transpose+convert W1 (256x128 fp32) -> Bt[256][128] bf16, k-contig.
// ---------------------------------------------------------------------------
__global__ __launch_bounds__(256) void transpose_w1(
    const float* __restrict__ W1, unsigned short* __restrict__ Bt)
{
    const int t  = threadIdx.x;
    const int nc = blockIdx.x * 4 + (t >> 6);
    const int k2 = (t & 63) * 2;
    const int col  = nc & 127;
    const int roff = (nc >= 128) ? 128 : 0;
    float f0 = W1[(size_t)(roff + k2)     * HIDDEN + col];
    float f1 = W1[(size_t)(roff + k2 + 1) * HIDDEN + col];
    *(unsigned*)(Bt + (size_t)nc * HIDDEN + k2) = (unsigned)f2b(f0) | ((unsigned)f2b(f1) << 16);
}

// ---------------------------------------------------------------------------
// Kernel 1 (MFMA GEMM, persistent): UV = z @ [W1src|W1dst] + [b1|0] -> uint8.
// R14: occupancy was register-bound, not LDS-bound (R13: VGPR_Count=112
// EXCLUDES the 64 acc AGPRs -> ~176 total -> 2 waves/SIMD -> 8 waves/CU in
// R11/R12/R13 alike; R12's (256,4) forced 128 total and spilled).
// Restructure: 512-thread blocks, 8 waves split the FEATURE dim (2x4 frags
// per wave: acc 32 + W-frags 32 regs). MFMA operands swapped (A=W, B=z;
// frag addressing is symmetric) so C = [feature][node]: each node's features
// are in-lane -> per-node absmax = 7 fmax + 2 shfl + 2 KB LDS partial
// round-trip. Kills the 32 KB fp32 C-staging, 64 ds_writes/lane epilogue,
// 8 b128 re-reads, 5-deep shfl chains; 2 barriers/tile instead of 4.
// Total regs ~115 <= 128 -> __launch_bounds__(512,4) = 16 waves/CU, no spill.
// ---------------------------------------------------------------------------
#define AS_STRIDE 136

__global__ __launch_bounds__(512, 4) void precompute_uv_mfma(
    const float* __restrict__ z, const unsigned short* __restrict__ Bt,
    const float* __restrict__ b1, unsigned char* __restrict__ UVq,
    float* __restrict__ scales)
{
    __shared__ unsigned short smem[64 * AS_STRIDE];   // 17.4 KB A-stage
    __shared__ float ppart[8 * 64];                   // 2 KB per-wave per-node partial max
    const int t = threadIdx.x;
    const int lane = t & 63;
    const int w = t >> 6;            // 0..7; waves 0-3 = U features, 4-7 = V
    const int wm = w * 32;           // wave's feature base
    const int g  = lane >> 4;
    const int lc = lane & 15;
    const int grp = w >> 2;          // 0 = U half, 1 = V half

    // --- W fragments (A-operand) + bias: once per block ---
    frag_ab b[2][4];                 // [mt][q]
    float bias[2][4];                // [mt][r], feature = wm + mt*16 + g*4 + r
    #pragma unroll
    for (int mt = 0; mt < 2; ++mt) {
        const int nc = wm + mt * 16 + lc;
        const unsigned short* brow = Bt + (size_t)nc * HIDDEN;
        #pragma unroll
        for (int q = 0; q < 4; ++q)
            b[mt][q] = *(const frag_ab*)(brow + q * 32 + g * 8);
        #pragma unroll
        for (int r = 0; r < 4; ++r)
            bias[mt][r] = (w < 4) ? b1[wm + mt * 16 + g * 4 + r] : 0.f;
    }

    int tile = blockIdx.x;
    uint2 pf[4];   // next A tile, already packed bf16 (8 VGPRs)
    #pragma unroll
    for (int i = 0; i < 4; ++i) {
        int f4 = i * 512 + t;
        int m = tile * 64 + (f4 >> 5);
        if (m >= N_NODES) m = N_NODES - 1;
        float4 v = ((const float4*)z)[(size_t)m * 32 + (f4 & 31)];
        pf[i].x = pk2(v.x, v.y);
        pf[i].y = pk2(v.z, v.w);
    }

    while (true) {
        // --- stage A: packed regs -> LDS ---
        #pragma unroll
        for (int i = 0; i < 4; ++i) {
            int f4 = i * 512 + t;
            *(uint2*)&smem[(f4 >> 5) * AS_STRIDE + (f4 & 31) * 4] = pf[i];
        }
        __syncthreads();   // S1: stage done; also guarantees prior-tile ppart reads done

        // --- prefetch NEXT tile (hides HBM latency behind MFMA+epilogue) ---
        const int next = tile + PC_GRID;
        const bool have_next = (next < N_TILES);
        if (have_next) {
            #pragma unroll
            for (int i = 0; i < 4; ++i) {
                int f4 = i * 512 + t;
                int m = next * 64 + (f4 >> 5);
                if (m >= N_NODES) m = N_NODES - 1;
                float4 v = ((const float4*)z)[(size_t)m * 32 + (f4 & 31)];
                pf[i].x = pk2(v.x, v.y);
                pf[i].y = pk2(v.z, v.w);
            }
        }

        // --- K loop: per wave 16 ds_read_b128 + 32 MFMA (A=W-frag, B=z-frag) ---
        frag_cd acc[2][4];
        #pragma unroll
        for (int mt = 0; mt < 2; ++mt)
            #pragma unroll
            for (int nt = 0; nt < 4; ++nt)
                acc[mt][nt] = (frag_cd){0.f, 0.f, 0.f, 0.f};
        #pragma unroll
        for (int q = 0; q < 4; ++q) {
            frag_ab a[4];
            #pragma unroll
            for (int nt = 0; nt < 4; ++nt)
                a[nt] = *(const frag_ab*)&smem[(nt * 16 + lc) * AS_STRIDE + q * 32 + g * 8];
            #pragma unroll
            for (int mt = 0; mt < 2; ++mt)
                #pragma unroll
                for (int nt = 0; nt < 4; ++nt)
                    acc[mt][nt] = __builtin_amdgcn_mfma_f32_16x16x32_bf16(
                        b[mt][q], a[nt], acc[mt][nt], 0, 0, 0);
        }
        // C layout: row(feature-within-wave) = mt*16 + g*4 + r, col(node) = nt*16 + lc

        // --- per-node wave-partial absmax: 8 in-lane values + 2 shfl across g ---
        const int m0 = tile * 64;
        float red[4];
        #pragma unroll
        for (int nt = 0; nt < 4; ++nt) {
            float mx = 0.f;
            #pragma unroll
            for (int mt = 0; mt < 2; ++mt)
                #pragma unroll
                for (int r = 0; r < 4; ++r)
                    mx = fmaxf(mx, fabsf(acc[mt][nt][r] + bias[mt][r]));
            mx = fmaxf(mx, __shfl_xor(mx, 16));
            mx = fmaxf(mx, __shfl_xor(mx, 32));
            red[nt] = mx;
        }
        if (g == 0) {
            #pragma unroll
            for (int nt = 0; nt < 4; ++nt)
                ppart[w * 64 + nt * 16 + lc] = red[nt];
        }
        __syncthreads();   // S3: partials visible; also fences A-region reuse

        // --- combine 4 waves per half, quantize, scattered dword stores ---
        #pragma unroll
        for (int nt = 0; nt < 4; ++nt) {
            const int idx  = nt * 16 + lc;
            const int node = m0 + idx;
            float mx = fmaxf(fmaxf(ppart[(grp * 4 + 0) * 64 + idx],
                                   ppart[(grp * 4 + 1) * 64 + idx]),
                             fmaxf(ppart[(grp * 4 + 2) * 64 + idx],
                                   ppart[(grp * 4 + 3) * 64 + idx]));
            mx = fmaxf(mx, 1e-12f);
            const float ainv = 127.0f / mx;
            if (node < N_NODES) {
                #pragma unroll
                for (int mt = 0; mt < 2; ++mt) {
                    unsigned q0 = (unsigned)__builtin_fmaf(acc[mt][nt][0] + bias[mt][0], ainv, 128.5f);
                    unsigned q1 = (unsigned)__builtin_fmaf(acc[mt][nt][1] + bias[mt][1], ainv, 128.5f);
                    unsigned q2 = (unsigned)__builtin_fmaf(acc[mt][nt][2] + bias[mt][2], ainv, 128.5f);
                    unsigned q3 = (unsigned)__builtin_fmaf(acc[mt][nt][3] + bias[mt][3], ainv, 128.5f);
                    unsigned pack = q0 | (q1 << 8) | (q2 << 16) | (q3 << 24);
                    *(unsigned*)&UVq[(size_t)node * 256 + wm + mt * 16 + g * 4] = pack;
                }
                if (g == 0 && (w == 0 || w == 4))
                    scales[node * 2 + grp] = mx * (1.0f / 127.0f);
            }
        }

        if (!have_next) break;
        tile = next;
    }
}

// ---------------------------------------------------------------------------
// Kernel 2: per-edge score = relu(aU*(u-128) + aV*(v-128)) . W2 + b2
// UNCHANGED from R11 (no longer the top kernel).
// ---------------------------------------------------------------------------
__device__ inline float dq4(unsigned uq, unsigned vq, float aU, float aV,
                            float k, float4 w, float acc) {
    #pragma unroll
    for (int b = 0; b < 4; ++b) {
        float uf = (float)((uq >> (8 * b)) & 0xffu);
        float vf = (float)((vq >> (8 * b)) & 0xffu);
        float h  = __builtin_fmaf(aU, uf, __builtin_fmaf(aV, vf, k));
        h = fmaxf(h, 0.f);
        float wv = (b == 0) ? w.x : (b == 1) ? w.y : (b == 2) ? w.z : w.w;
        acc = __builtin_fmaf(h, wv, acc);
    }
    return acc;
}

__global__ __launch_bounds__(256) void edge_score(
    const int* __restrict__ ei, const unsigned char* __restrict__ UVq,
    const float* __restrict__ scales, const float* __restrict__ W2,
    const float* __restrict__ B2, float* __restrict__ out)
{
    const int t = threadIdx.x;
    const int g = t & 7;
    const int slot = t >> 3;
    const int e0 = blockIdx.x * 64 + slot;
    const int e1 = e0 + 32;

    const float4* W24 = (const float4*)W2;
    const float4 w0 = W24[g * 4 + 0];
    const float4 w1 = W24[g * 4 + 1];
    const float4 w2 = W24[g * 4 + 2];
    const float4 w3 = W24[g * 4 + 3];

    const int s0 = ei[e0];
    const int d0 = ei[N_EDGES + e0];
    const int s1 = ei[e1];
    const int d1 = ei[N_EDGES + e1];

    // 16 B/lane x 8 lanes = one 128 B row-half per edge side (1 dwordx4 each)
    const uint4 u0 = *(const uint4*)(UVq + (size_t)s0 * 256 + g * 16);
    const uint4 v0 = *(const uint4*)(UVq + (size_t)d0 * 256 + 128 + g * 16);
    const uint4 u1 = *(const uint4*)(UVq + (size_t)s1 * 256 + g * 16);
    const uint4 v1 = *(const uint4*)(UVq + (size_t)d1 * 256 + 128 + g * 16);
    const float aU0 = scales[s0 * 2];
    const float aV0 = scales[d0 * 2 + 1];
    const float aU1 = scales[s1 * 2];
    const float aV1 = scales[d1 * 2 + 1];

    const float k0 = -128.f * (aU0 + aV0);
    const float k1 = -128.f * (aU1 + aV1);

    float A = 0.f, B = 0.f;
    A = dq4(u0.x, v0.x, aU0, aV0, k0, w0, A);
    A = dq4(u0.y, v0.y, aU0, aV0, k0, w1, A);
    A = dq4(u0.z, v0.z, aU0, aV0, k0, w2, A);
    A = dq4(u0.w, v0.w, aU0, aV0, k0, w3, A);

    B = dq4(u1.x, v1.x, aU1, aV1, k1, w0, B);
    B = dq4(u1.y, v1.y, aU1, aV1, k1, w1, B);
    B = dq4(u1.z, v1.z, aU1, aV1, k1, w2, B);
    B = dq4(u1.w, v1.w, aU1, aV1, k1, w3, B);

    float sa = A;
    float sb = B;
    sa += __shfl_xor(sa, 1, 8);
    sa += __shfl_xor(sa, 2, 8);
    sa += __shfl_xor(sa, 4, 8);
    sb += __shfl_xor(sb, 1, 8);
    sb += __shfl_xor(sb, 2, 8);
    sb += __shfl_xor(sb, 4, 8);

    if (g == 0) {
        float bb = B2[0];
        out[e0] = sa + bb;
        out[e1] = sb + bb;
    }
}

extern "C" void kernel_launch(void* const* d_in, const int* in_sizes, int n_in,
                              void* d_out, int out_size, void* d_ws, size_t ws_size,
                              hipStream_t stream) {
    const float* z  = (const float*)d_in[0];
    const int*   ei = (const int*)d_in[1];
    const float* W1 = (const float*)d_in[2];
    const float* b1 = (const float*)d_in[3];
    const float* W2 = (const float*)d_in[4];
    const float* b2 = (const float*)d_in[5];
    float* out = (float*)d_out;

    unsigned char* UVq = (unsigned char*)d_ws;                       // 25.6 MB
    float* scales = (float*)(UVq + (size_t)N_NODES * 256);           // 800 KB (U,V scale pairs)
    unsigned short* Bt = (unsigned short*)(scales + 2 * N_NODES);    // 64 KB, 16B-aligned

    transpose_w1<<<64, 256, 0, stream>>>(W1, Bt);
    precompute_uv_mfma<<<PC_GRID, 512, 0, stream>>>(z, Bt, b1, UVq, scales);
    edge_score<<<N_EDGES / 64, 256, 0, stream>>>(ei, UVq, scales, W2, b2, out);
}